// Round 1
// baseline (7525.068 us; speedup 1.0000x reference)
//
#include <hip/hip_runtime.h>

#define B_N   32768
#define HID   512
#define DIM   256
#define MAXN  17
#define SM    264   // SP_MID == KEY_MID
#define DM    384   // DEC_MID

// ---------------------------------------------------------------------------
// Stage 1: size_pred MLP + argmax.  16 samples / workgroup, 320 threads.
// u = z @ sp_W1 + b1 ; LN ; relu ; n_pred = h @ sp_W2 + b2 ; n = argmax
// ---------------------------------------------------------------------------
__global__ __launch_bounds__(320) void sizepred_kernel(
    const float* __restrict__ z,  const float* __restrict__ W1,
    const float* __restrict__ b1, const float* __restrict__ g1,
    const float* __restrict__ be1, const float* __restrict__ W2,
    const float* __restrict__ b2, int* __restrict__ n_out)
{
  __shared__ __align__(16) float zs[16 * 512];   // 32 KB  z tile [s][c]
  __shared__ __align__(16) float wch[8 * 264];   // 8.25 KB W1 chunk [cc][j] (reused for n_pred)
  __shared__ __align__(16) float us[16 * 265];   // 16.6 KB u / h [s][j] (+1 pad)
  __shared__ float lnm[16], lnr[16];

  const int tid = threadIdx.x;
  const int b0  = blockIdx.x * 16;

  // load z tile, coalesced float4
  for (int idx = tid; idx < 2048; idx += 320) {
    int rr = idx >> 7, c4 = idx & 127;
    float4 v = ((const float4*)z)[(size_t)(b0 + rr) * 128 + c4];
    *(float4*)&zs[rr * 512 + c4 * 4] = v;
  }

  float acc[4][4];
#pragma unroll
  for (int i = 0; i < 4; ++i)
#pragma unroll
    for (int q = 0; q < 4; ++q) acc[i][q] = 0.f;

  const bool act = tid < 264;               // 66 j-blocks x 4 s-groups
  const int  s0  = (tid / 66) * 4;
  const int  j0  = (tid % 66) * 4;

  for (int c0 = 0; c0 < 512; c0 += 8) {
    __syncthreads();
    // stage W1 rows c0..c0+7 (contiguous 2112 floats = 528 float4)
    for (int idx = tid; idx < 528; idx += 320)
      ((float4*)wch)[idx] = ((const float4*)(W1 + c0 * 264))[idx];
    __syncthreads();
    if (act) {
#pragma unroll
      for (int cc = 0; cc < 8; ++cc) {
        float a0 = zs[(s0 + 0) * 512 + c0 + cc];
        float a1 = zs[(s0 + 1) * 512 + c0 + cc];
        float a2 = zs[(s0 + 2) * 512 + c0 + cc];
        float a3 = zs[(s0 + 3) * 512 + c0 + cc];
        float4 bv = *(const float4*)&wch[cc * 264 + j0];
        acc[0][0] += a0 * bv.x; acc[0][1] += a0 * bv.y; acc[0][2] += a0 * bv.z; acc[0][3] += a0 * bv.w;
        acc[1][0] += a1 * bv.x; acc[1][1] += a1 * bv.y; acc[1][2] += a1 * bv.z; acc[1][3] += a1 * bv.w;
        acc[2][0] += a2 * bv.x; acc[2][1] += a2 * bv.y; acc[2][2] += a2 * bv.z; acc[2][3] += a2 * bv.w;
        acc[3][0] += a3 * bv.x; acc[3][1] += a3 * bv.y; acc[3][2] += a3 * bv.z; acc[3][3] += a3 * bv.w;
      }
    }
  }

  if (act) {
    float4 bb = *(const float4*)&b1[j0];
#pragma unroll
    for (int i = 0; i < 4; ++i) {
      us[(s0 + i) * 265 + j0 + 0] = acc[i][0] + bb.x;
      us[(s0 + i) * 265 + j0 + 1] = acc[i][1] + bb.y;
      us[(s0 + i) * 265 + j0 + 2] = acc[i][2] + bb.z;
      us[(s0 + i) * 265 + j0 + 3] = acc[i][3] + bb.w;
    }
  }
  __syncthreads();

  if (tid < 16) {
    float s = 0.f, q = 0.f;
    for (int j = 0; j < 264; ++j) { float v = us[tid * 265 + j]; s += v; q += v * v; }
    float m   = s / 264.f;
    float var = q / 264.f - m * m;
    lnm[tid] = m;
    lnr[tid] = 1.f / sqrtf(var + 1e-5f);
  }
  __syncthreads();

  for (int idx = tid; idx < 16 * 264; idx += 320) {
    int s = idx / 264, j = idx - s * 264;
    float v = (us[s * 265 + j] - lnm[s]) * lnr[s] * g1[j] + be1[j];
    us[s * 265 + j] = fmaxf(v, 0.f);
  }
  __syncthreads();

  // n_pred: 16 samples x 17 logits = 272 tasks (store into wch)
  if (tid < 272) {
    int s = tid / 17, jj = tid - s * 17;
    float a = b2[jj];
    for (int c = 0; c < 264; ++c) a += us[s * 265 + c] * W2[c * 17 + jj];
    wch[s * 17 + jj] = a;
  }
  __syncthreads();

  if (tid < 16) {
    int best = 0; float bv = wch[tid * 17];
    for (int jj = 1; jj < 17; ++jj) {
      float v = wch[tid * 17 + jj];
      if (v > bv) { bv = v; best = jj; }   // first-max == np.argmax
    }
    n_out[b0 + tid] = best;
  }
}

// ---------------------------------------------------------------------------
// Stage 2: exclusive prefix sum of n[32768] -> starts[32769]. One block.
// ---------------------------------------------------------------------------
__global__ __launch_bounds__(1024) void scan_kernel(const int* __restrict__ n,
                                                    int* __restrict__ starts)
{
  __shared__ int part[1024];
  const int tid  = threadIdx.x;
  const int base = tid * 32;
  int loc[32];
  int s = 0;
#pragma unroll
  for (int i = 0; i < 32; ++i) { loc[i] = n[base + i]; s += loc[i]; }
  part[tid] = s;
  __syncthreads();
  for (int off = 1; off < 1024; off <<= 1) {
    int v   = part[tid];
    int add = (tid >= off) ? part[tid - off] : 0;
    __syncthreads();
    part[tid] = v + add;
    __syncthreads();
  }
  int run = part[tid] - s;   // exclusive base
#pragma unroll
  for (int i = 0; i < 32; ++i) { starts[base + i] = run; run += loc[i]; }
  if (tid == 1023) starts[B_N] = run;
}

// ---------------------------------------------------------------------------
// Stage 3: scatter ragged indices + write batch output (as float) at end of out
// ---------------------------------------------------------------------------
__global__ __launch_bounds__(256) void scatter_kernel(
    const int* __restrict__ n, const int* __restrict__ starts,
    int* __restrict__ bi, int* __restrict__ ki, float* __restrict__ out, int T)
{
  int b = blockIdx.x * 256 + threadIdx.x;
  if (b >= B_N) return;
  int st = starts[b], nn = n[b];
  float* ob = out + (size_t)T * DIM;
  for (int k = 0; k < nn; ++k) {
    bi[st + k] = b;
    ki[st + k] = k;
    ob[st + k] = (float)b;
  }
}

// ---------------------------------------------------------------------------
// Stage 4: keys table [17][512].  one_hot(k) @ key_W1 == key_W1 row k.
// ---------------------------------------------------------------------------
__global__ __launch_bounds__(320) void keys_kernel(
    const float* __restrict__ W1, const float* __restrict__ b1,
    const float* __restrict__ g1, const float* __restrict__ be1,
    const float* __restrict__ W2, const float* __restrict__ b2,
    float* __restrict__ ktab)
{
  __shared__ float hs[264];
  __shared__ float mr[2];
  const int kk = blockIdx.x, tid = threadIdx.x;
  if (tid < 264) hs[tid] = W1[kk * 264 + tid] + b1[tid];
  __syncthreads();
  if (tid == 0) {
    float s = 0.f, q = 0.f;
    for (int j = 0; j < 264; ++j) { float v = hs[j]; s += v; q += v * v; }
    float m = s / 264.f;
    mr[0] = m;
    mr[1] = 1.f / sqrtf(q / 264.f - m * m + 1e-5f);
  }
  __syncthreads();
  if (tid < 264) hs[tid] = fmaxf((hs[tid] - mr[0]) * mr[1] * g1[tid] + be1[tid], 0.f);
  __syncthreads();
  for (int c = tid; c < 512; c += 320) {
    float a = b2[c];
    for (int j = 0; j < 264; ++j) a += hs[j] * W2[j * 512 + c];
    ktab[kk * 512 + c] = a;
  }
}

// ---------------------------------------------------------------------------
// Stage 5: decoder.  16 rows / workgroup, 384 threads.
// zp = z[batch]*keys[k]; h = relu(zp@W1+b1); x = h@W2+b2
// LDS: zp 32KB | wch 24KB ; h2 aliases zp (phase-1 done) -> 57.4 KB total
// ---------------------------------------------------------------------------
__global__ __launch_bounds__(384) void decoder_kernel(
    const float* __restrict__ z,  const float* __restrict__ ktab,
    const float* __restrict__ W1, const float* __restrict__ b1,
    const float* __restrict__ W2, const float* __restrict__ b2,
    const int* __restrict__ bi,   const int* __restrict__ ki,
    float* __restrict__ out, int T)
{
  __shared__ __align__(16) float smem[14336];  // 57344 B
  float* zp  = smem;          // [16][512]
  float* wch = smem + 8192;   // [16][384] max (also [16][256] in phase 2)
  float* h2  = smem;          // [16][384], aliases zp after phase 1
  __shared__ int tb[16], tk[16];

  const int tid = threadIdx.x;
  const int t0  = blockIdx.x * 16;

  if (tid < 16) {
    int t = t0 + tid;
    tb[tid] = (t < T) ? bi[t] : 0;
    tk[tid] = (t < T) ? ki[t] : 0;
  }
  __syncthreads();

  // zp = z[batch] * keys[k], float4
  for (int idx = tid; idx < 2048; idx += 384) {
    int rr = idx >> 7, c4 = idx & 127;
    float4 zv = ((const float4*)z)[(size_t)tb[rr] * 128 + c4];
    float4 kv = ((const float4*)ktab)[(size_t)tk[rr] * 128 + c4];
    float4 r;
    r.x = zv.x * kv.x; r.y = zv.y * kv.y; r.z = zv.z * kv.z; r.w = zv.w * kv.w;
    *(float4*)&zp[rr * 512 + c4 * 4] = r;
  }

  // ---- phase 1: h = relu(zp @ W1 + b1), 16x384, tile 4x4, 4x96 threads ----
  float acc[4][4];
#pragma unroll
  for (int i = 0; i < 4; ++i)
#pragma unroll
    for (int q = 0; q < 4; ++q) acc[i][q] = 0.f;

  const int r0 = (tid / 96) * 4;
  const int j0 = (tid % 96) * 4;

  for (int c0 = 0; c0 < 512; c0 += 16) {
    __syncthreads();
    for (int idx = tid; idx < 1536; idx += 384)
      ((float4*)wch)[idx] = ((const float4*)(W1 + c0 * 384))[idx];
    __syncthreads();
#pragma unroll
    for (int cc = 0; cc < 16; ++cc) {
      float a0 = zp[(r0 + 0) * 512 + c0 + cc];
      float a1 = zp[(r0 + 1) * 512 + c0 + cc];
      float a2 = zp[(r0 + 2) * 512 + c0 + cc];
      float a3 = zp[(r0 + 3) * 512 + c0 + cc];
      float4 bv = *(const float4*)&wch[cc * 384 + j0];
      acc[0][0] += a0 * bv.x; acc[0][1] += a0 * bv.y; acc[0][2] += a0 * bv.z; acc[0][3] += a0 * bv.w;
      acc[1][0] += a1 * bv.x; acc[1][1] += a1 * bv.y; acc[1][2] += a1 * bv.z; acc[1][3] += a1 * bv.w;
      acc[2][0] += a2 * bv.x; acc[2][1] += a2 * bv.y; acc[2][2] += a2 * bv.z; acc[2][3] += a2 * bv.w;
      acc[3][0] += a3 * bv.x; acc[3][1] += a3 * bv.y; acc[3][2] += a3 * bv.z; acc[3][3] += a3 * bv.w;
    }
  }
  __syncthreads();   // all zp reads complete before h2 (alias) is written

  {
    float4 bb = *(const float4*)&b1[j0];
#pragma unroll
    for (int i = 0; i < 4; ++i) {
      h2[(r0 + i) * 384 + j0 + 0] = fmaxf(acc[i][0] + bb.x, 0.f);
      h2[(r0 + i) * 384 + j0 + 1] = fmaxf(acc[i][1] + bb.y, 0.f);
      h2[(r0 + i) * 384 + j0 + 2] = fmaxf(acc[i][2] + bb.z, 0.f);
      h2[(r0 + i) * 384 + j0 + 3] = fmaxf(acc[i][3] + bb.w, 0.f);
    }
  }

  // ---- phase 2: x = h2 @ W2 + b2, 16x256, tile 4x4, 4x64 threads (256) ----
  float acc2[4][4];
#pragma unroll
  for (int i = 0; i < 4; ++i)
#pragma unroll
    for (int q = 0; q < 4; ++q) acc2[i][q] = 0.f;

  const bool act2 = tid < 256;
  const int  r02  = ((tid & 255) / 64) * 4;
  const int  j02  = (tid % 64) * 4;

  for (int c0 = 0; c0 < 384; c0 += 16) {
    __syncthreads();   // also covers h2 stores on first iteration
    for (int idx = tid; idx < 1024; idx += 384)
      ((float4*)wch)[idx] = ((const float4*)(W2 + c0 * 256))[idx];
    __syncthreads();
    if (act2) {
#pragma unroll
      for (int cc = 0; cc < 16; ++cc) {
        float a0 = h2[(r02 + 0) * 384 + c0 + cc];
        float a1 = h2[(r02 + 1) * 384 + c0 + cc];
        float a2 = h2[(r02 + 2) * 384 + c0 + cc];
        float a3 = h2[(r02 + 3) * 384 + c0 + cc];
        float4 bv = *(const float4*)&wch[cc * 256 + j02];
        acc2[0][0] += a0 * bv.x; acc2[0][1] += a0 * bv.y; acc2[0][2] += a0 * bv.z; acc2[0][3] += a0 * bv.w;
        acc2[1][0] += a1 * bv.x; acc2[1][1] += a1 * bv.y; acc2[1][2] += a1 * bv.z; acc2[1][3] += a1 * bv.w;
        acc2[2][0] += a2 * bv.x; acc2[2][1] += a2 * bv.y; acc2[2][2] += a2 * bv.z; acc2[2][3] += a2 * bv.w;
        acc2[3][0] += a3 * bv.x; acc2[3][1] += a3 * bv.y; acc2[3][2] += a3 * bv.z; acc2[3][3] += a3 * bv.w;
      }
    }
  }

  if (act2) {
    float4 bb = *(const float4*)&b2[j02];
#pragma unroll
    for (int i = 0; i < 4; ++i) {
      int t = t0 + r02 + i;
      if (t < T) {
        float4 o;
        o.x = acc2[i][0] + bb.x; o.y = acc2[i][1] + bb.y;
        o.z = acc2[i][2] + bb.z; o.w = acc2[i][3] + bb.w;
        ((float4*)out)[(size_t)t * 64 + (j02 >> 2)] = o;
      }
    }
  }
}

// ---------------------------------------------------------------------------
extern "C" void kernel_launch(void* const* d_in, const int* in_sizes, int n_in,
                              void* d_out, int out_size, void* d_ws, size_t ws_size,
                              hipStream_t stream)
{
  const float* z      = (const float*)d_in[0];
  const float* keyW1  = (const float*)d_in[1];
  const float* keyb1  = (const float*)d_in[2];
  const float* keyg1  = (const float*)d_in[3];
  const float* keybe1 = (const float*)d_in[4];
  const float* keyW2  = (const float*)d_in[5];
  const float* keyb2  = (const float*)d_in[6];
  const float* decW1  = (const float*)d_in[7];
  const float* decb1  = (const float*)d_in[8];
  const float* decW2  = (const float*)d_in[9];
  const float* decb2  = (const float*)d_in[10];
  const float* spW1   = (const float*)d_in[11];
  const float* spb1   = (const float*)d_in[12];
  const float* spg1   = (const float*)d_in[13];
  const float* spbe1  = (const float*)d_in[14];
  const float* spW2   = (const float*)d_in[15];
  const float* spb2   = (const float*)d_in[16];

  const int T = out_size / (DIM + 1);   // out = x[T,256] ++ batch[T]

  char* ws = (char*)d_ws;
  int*   n_arr  = (int*)(ws);                         // 32768 ints
  int*   starts = (int*)(ws + 131072);                // 32769 ints
  float* ktab   = (float*)(ws + 262160);              // 17*512 floats (16B aligned)
  int*   bi     = (int*)(ws + 296976);                // T ints
  size_t kioff  = 296976 + (((size_t)T * 4 + 15) / 16) * 16;
  int*   ki     = (int*)(ws + kioff);                 // T ints

  float* outF = (float*)d_out;

  sizepred_kernel<<<B_N / 16, 320, 0, stream>>>(z, spW1, spb1, spg1, spbe1, spW2, spb2, n_arr);
  scan_kernel<<<1, 1024, 0, stream>>>(n_arr, starts);
  scatter_kernel<<<B_N / 256, 256, 0, stream>>>(n_arr, starts, bi, ki, outF, T);
  keys_kernel<<<MAXN, 320, 0, stream>>>(keyW1, keyb1, keyg1, keybe1, keyW2, keyb2, ktab);
  decoder_kernel<<<(T + 15) / 16, 384, 0, stream>>>(z, ktab, decW1, decb1, decW2, decb2, bi, ki, outF, T);
}

// Round 3
// 1451.019 us; speedup vs baseline: 5.1861x; 5.1861x over previous
//
#include <hip/hip_runtime.h>

#define B_N   32768
#define HID   512
#define DIM   256
#define MAXN  17
#define SM    264   // SP_MID == KEY_MID
#define DM    384   // DEC_MID

typedef __attribute__((ext_vector_type(8))) short bf16x8;
typedef __attribute__((ext_vector_type(4))) float f32x4;

static __device__ __forceinline__ unsigned short f2bf(float x) {
  union { float f; unsigned u; } v; v.f = x;
  unsigned r = (v.u + 0x7FFFu + ((v.u >> 16) & 1u)) >> 16;   // RNE
  return (unsigned short)r;
}

// ---------------------------------------------------------------------------
// Stage 1: size_pred MLP + argmax.  16 samples / workgroup, 320 threads.
// MUST stay fp32: argmax flips would corrupt the ragged layout.
// ---------------------------------------------------------------------------
__global__ __launch_bounds__(320) void sizepred_kernel(
    const float* __restrict__ z,  const float* __restrict__ W1,
    const float* __restrict__ b1, const float* __restrict__ g1,
    const float* __restrict__ be1, const float* __restrict__ W2,
    const float* __restrict__ b2, int* __restrict__ n_out)
{
  __shared__ __align__(16) float zs[16 * 512];
  __shared__ __align__(16) float wch[8 * 264];
  __shared__ __align__(16) float us[16 * 265];
  __shared__ float lnm[16], lnr[16];

  const int tid = threadIdx.x;
  const int b0  = blockIdx.x * 16;

  for (int idx = tid; idx < 2048; idx += 320) {
    int rr = idx >> 7, c4 = idx & 127;
    float4 v = ((const float4*)z)[(size_t)(b0 + rr) * 128 + c4];
    *(float4*)&zs[rr * 512 + c4 * 4] = v;
  }

  float acc[4][4];
#pragma unroll
  for (int i = 0; i < 4; ++i)
#pragma unroll
    for (int q = 0; q < 4; ++q) acc[i][q] = 0.f;

  const bool act = tid < 264;
  const int  s0  = (tid / 66) * 4;
  const int  j0  = (tid % 66) * 4;

  for (int c0 = 0; c0 < 512; c0 += 8) {
    __syncthreads();
    for (int idx = tid; idx < 528; idx += 320)
      ((float4*)wch)[idx] = ((const float4*)(W1 + c0 * 264))[idx];
    __syncthreads();
    if (act) {
#pragma unroll
      for (int cc = 0; cc < 8; ++cc) {
        float a0 = zs[(s0 + 0) * 512 + c0 + cc];
        float a1 = zs[(s0 + 1) * 512 + c0 + cc];
        float a2 = zs[(s0 + 2) * 512 + c0 + cc];
        float a3 = zs[(s0 + 3) * 512 + c0 + cc];
        float4 bv = *(const float4*)&wch[cc * 264 + j0];
        acc[0][0] += a0 * bv.x; acc[0][1] += a0 * bv.y; acc[0][2] += a0 * bv.z; acc[0][3] += a0 * bv.w;
        acc[1][0] += a1 * bv.x; acc[1][1] += a1 * bv.y; acc[1][2] += a1 * bv.z; acc[1][3] += a1 * bv.w;
        acc[2][0] += a2 * bv.x; acc[2][1] += a2 * bv.y; acc[2][2] += a2 * bv.z; acc[2][3] += a2 * bv.w;
        acc[3][0] += a3 * bv.x; acc[3][1] += a3 * bv.y; acc[3][2] += a3 * bv.z; acc[3][3] += a3 * bv.w;
      }
    }
  }

  if (act) {
    float4 bb = *(const float4*)&b1[j0];
#pragma unroll
    for (int i = 0; i < 4; ++i) {
      us[(s0 + i) * 265 + j0 + 0] = acc[i][0] + bb.x;
      us[(s0 + i) * 265 + j0 + 1] = acc[i][1] + bb.y;
      us[(s0 + i) * 265 + j0 + 2] = acc[i][2] + bb.z;
      us[(s0 + i) * 265 + j0 + 3] = acc[i][3] + bb.w;
    }
  }
  __syncthreads();

  if (tid < 16) {
    float s = 0.f, q = 0.f;
    for (int j = 0; j < 264; ++j) { float v = us[tid * 265 + j]; s += v; q += v * v; }
    float m   = s / 264.f;
    float var = q / 264.f - m * m;
    lnm[tid] = m;
    lnr[tid] = 1.f / sqrtf(var + 1e-5f);
  }
  __syncthreads();

  for (int idx = tid; idx < 16 * 264; idx += 320) {
    int s = idx / 264, j = idx - s * 264;
    float v = (us[s * 265 + j] - lnm[s]) * lnr[s] * g1[j] + be1[j];
    us[s * 265 + j] = fmaxf(v, 0.f);
  }
  __syncthreads();

  if (tid < 272) {
    int s = tid / 17, jj = tid - s * 17;
    float a = b2[jj];
    for (int c = 0; c < 264; ++c) a += us[s * 265 + c] * W2[c * 17 + jj];
    wch[s * 17 + jj] = a;
  }
  __syncthreads();

  if (tid < 16) {
    int best = 0; float bv = wch[tid * 17];
    for (int jj = 1; jj < 17; ++jj) {
      float v = wch[tid * 17 + jj];
      if (v > bv) { bv = v; best = jj; }
    }
    n_out[b0 + tid] = best;
  }
}

// ---------------------------------------------------------------------------
// Stage 2: exclusive prefix sum of n[32768] -> starts[32769]. One block.
// ---------------------------------------------------------------------------
__global__ __launch_bounds__(1024) void scan_kernel(const int* __restrict__ n,
                                                    int* __restrict__ starts)
{
  __shared__ int part[1024];
  const int tid  = threadIdx.x;
  const int base = tid * 32;
  int loc[32];
  int s = 0;
#pragma unroll
  for (int i = 0; i < 32; ++i) { loc[i] = n[base + i]; s += loc[i]; }
  part[tid] = s;
  __syncthreads();
  for (int off = 1; off < 1024; off <<= 1) {
    int v   = part[tid];
    int add = (tid >= off) ? part[tid - off] : 0;
    __syncthreads();
    part[tid] = v + add;
    __syncthreads();
  }
  int run = part[tid] - s;
#pragma unroll
  for (int i = 0; i < 32; ++i) { starts[base + i] = run; run += loc[i]; }
  if (tid == 1023) starts[B_N] = run;
}

// ---------------------------------------------------------------------------
// Stage 3: scatter ragged indices + write batch output (as float)
// ---------------------------------------------------------------------------
__global__ __launch_bounds__(256) void scatter_kernel(
    const int* __restrict__ n, const int* __restrict__ starts,
    int* __restrict__ bi, int* __restrict__ ki, float* __restrict__ out, int T)
{
  int b = blockIdx.x * 256 + threadIdx.x;
  if (b >= B_N) return;
  int st = starts[b], nn = n[b];
  float* ob = out + (size_t)T * DIM;
  for (int k = 0; k < nn; ++k) {
    bi[st + k] = b;
    ki[st + k] = k;
    ob[st + k] = (float)b;
  }
}

// ---------------------------------------------------------------------------
// Stage 4: keys table [17][512]
// ---------------------------------------------------------------------------
__global__ __launch_bounds__(320) void keys_kernel(
    const float* __restrict__ W1, const float* __restrict__ b1,
    const float* __restrict__ g1, const float* __restrict__ be1,
    const float* __restrict__ W2, const float* __restrict__ b2,
    float* __restrict__ ktab)
{
  __shared__ float hs[264];
  __shared__ float mr[2];
  const int kk = blockIdx.x, tid = threadIdx.x;
  if (tid < 264) hs[tid] = W1[kk * 264 + tid] + b1[tid];
  __syncthreads();
  if (tid == 0) {
    float s = 0.f, q = 0.f;
    for (int j = 0; j < 264; ++j) { float v = hs[j]; s += v; q += v * v; }
    float m = s / 264.f;
    mr[0] = m;
    mr[1] = 1.f / sqrtf(q / 264.f - m * m + 1e-5f);
  }
  __syncthreads();
  if (tid < 264) hs[tid] = fmaxf((hs[tid] - mr[0]) * mr[1] * g1[tid] + be1[tid], 0.f);
  __syncthreads();
  for (int c = tid; c < 512; c += 320) {
    float a = b2[c];
    for (int j = 0; j < 264; ++j) a += hs[j] * W2[j * 512 + c];
    ktab[kk * 512 + c] = a;
  }
}

// ---------------------------------------------------------------------------
// Stage 4b: pack dec_W1/dec_W2 into bf16 MFMA B-fragment layout.
// Chunk (kt, nt, lane): 8 bf16 = W[kt*32 + (lane>>4)*8 + j][nt*16 + (lane&15)]
// W1p: 16 kt x 24 nt ; W2p: 12 kt x 16 nt.  grid 576 x 64.
// ---------------------------------------------------------------------------
__global__ __launch_bounds__(64) void pack_kernel(
    const float* __restrict__ W1, const float* __restrict__ W2,
    short* __restrict__ W1p, short* __restrict__ W2p)
{
  const int g = blockIdx.x, l = threadIdx.x;
  const float* W; int nt, kt, N;
  if (g < 384) { W = W1; kt = g / 24; nt = g % 24; N = 384; }
  else         { W = W2; int gg = g - 384; kt = gg / 16; nt = gg % 16; N = 256; }
  const int krow = kt * 32 + ((l >> 4) << 3);
  const int col  = nt * 16 + (l & 15);
  short v[8];
#pragma unroll
  for (int j = 0; j < 8; ++j)
    v[j] = (short)f2bf(W[(size_t)(krow + j) * N + col]);
  short* d = (g < 384) ? (W1p + ((size_t)g * 64 + l) * 8)
                       : (W2p + ((size_t)(g - 384) * 64 + l) * 8);
  *(bf16x8*)d = *(bf16x8*)v;
}

// ---------------------------------------------------------------------------
// Stage 5: MFMA decoder.  32 rows / block, 256 threads (4 waves).
// zp staged in LDS pre-swizzled as A-fragments (bf16); W1p/W2p B-fragments
// streamed from L2; fp32 accumulate; H re-packed to LDS for phase 2.
// ---------------------------------------------------------------------------
__global__ __launch_bounds__(256) void decoder_kernel(
    const float* __restrict__ z,  const float* __restrict__ ktab,
    const short* __restrict__ W1p, const float* __restrict__ b1,
    const short* __restrict__ W2p, const float* __restrict__ b2,
    const int* __restrict__ bi,   const int* __restrict__ ki,
    float* __restrict__ out, int T)
{
  // zps: 2 mt x 16 kt x 64 lanes x 8 bf16 = 32 KB.  Hs (24 KB) aliases it.
  __shared__ __align__(16) short zps[16384];
  __shared__ int tb[32], tk[32];

  const int tid  = threadIdx.x;
  const int wave = tid >> 6;
  const int lane = tid & 63;
  const int t0   = blockIdx.x * 32;

  if (tid < 32) {
    int t = t0 + tid;
    tb[tid] = (t < T) ? bi[t] : 0;
    tk[tid] = (t < T) ? ki[t] : 0;
  }
  __syncthreads();

  // ---- stage zp = z[b]*ktab[k] into A-fragment layout ----
  // chunk = (kt*2 + mt)*64 + lane ; element j = zp[mt*16+(lane&15)][kt*32+(lane>>4)*8+j]
#pragma unroll
  for (int it = 0; it < 8; ++it) {
    int chunk = tid + it * 256;
    int l  = chunk & 63;
    int mt = (chunk >> 6) & 1;
    int kt = chunk >> 7;
    int m  = mt * 16 + (l & 15);
    int k0 = kt * 32 + ((l >> 4) << 3);
    const float4* zr = (const float4*)(z    + (size_t)tb[m] * 512 + k0);
    const float4* kr = (const float4*)(ktab + (size_t)tk[m] * 512 + k0);
    float4 z0 = zr[0], z1 = zr[1], k4 = kr[0], k5 = kr[1];
    short v[8];
    v[0] = (short)f2bf(z0.x * k4.x); v[1] = (short)f2bf(z0.y * k4.y);
    v[2] = (short)f2bf(z0.z * k4.z); v[3] = (short)f2bf(z0.w * k4.w);
    v[4] = (short)f2bf(z1.x * k5.x); v[5] = (short)f2bf(z1.y * k5.y);
    v[6] = (short)f2bf(z1.z * k5.z); v[7] = (short)f2bf(z1.w * k5.w);
    *(bf16x8*)&zps[(size_t)chunk * 8] = *(bf16x8*)v;
  }
  __syncthreads();

  // ---- phase 1: H = relu(zp @ W1 + b1).  wave covers cols [96w, 96w+96) ----
  f32x4 acc[2][6];
#pragma unroll
  for (int mt = 0; mt < 2; ++mt)
#pragma unroll
    for (int j = 0; j < 6; ++j) acc[mt][j] = (f32x4){0.f, 0.f, 0.f, 0.f};

  {
    const short* wb = W1p + ((size_t)(wave * 6) * 64 + lane) * 8;
#pragma unroll 4
    for (int kt = 0; kt < 16; ++kt) {
      bf16x8 a0 = *(bf16x8*)&zps[((kt * 2 + 0) * 64 + lane) * 8];
      bf16x8 a1 = *(bf16x8*)&zps[((kt * 2 + 1) * 64 + lane) * 8];
#pragma unroll
      for (int j = 0; j < 6; ++j) {
        bf16x8 bf = *(const bf16x8*)(wb + (size_t)kt * 12288 + j * 512);
        acc[0][j] = __builtin_amdgcn_mfma_f32_16x16x32_bf16(a0, bf, acc[0][j], 0, 0, 0);
        acc[1][j] = __builtin_amdgcn_mfma_f32_16x16x32_bf16(a1, bf, acc[1][j], 0, 0, 0);
      }
    }
  }
  __syncthreads();   // all zps reads done; Hs aliases zps

  // ---- epilogue 1: bias + relu + pack into phase-2 A-fragment layout ----
  {
    short* Hs = zps;
    float bload[6];
#pragma unroll
    for (int j = 0; j < 6; ++j)
      bload[j] = b1[wave * 96 + j * 16 + (lane & 15)];
#pragma unroll
    for (int mt = 0; mt < 2; ++mt) {
#pragma unroll
      for (int j = 0; j < 6; ++j) {
        int c = wave * 96 + j * 16 + (lane & 15);
        int lane2hi = ((c >> 3) & 3) << 4;
        int koff = (c >> 5) * 2;
        int jj = c & 7;
#pragma unroll
        for (int r = 0; r < 4; ++r) {
          int m = mt * 16 + (lane >> 4) * 4 + r;
          float v = fmaxf(acc[mt][j][r] + bload[j], 0.f);
          Hs[((koff + (m >> 4)) * 64 + ((m & 15) | lane2hi)) * 8 + jj] = (short)f2bf(v);
        }
      }
    }
  }
  __syncthreads();

  // ---- phase 2: x = H @ W2 + b2.  wave covers cols [64w, 64w+64) ----
  f32x4 acc2[2][4];
#pragma unroll
  for (int mt = 0; mt < 2; ++mt)
#pragma unroll
    for (int j = 0; j < 4; ++j) acc2[mt][j] = (f32x4){0.f, 0.f, 0.f, 0.f};

  {
    const short* Hs = zps;
    const short* wb = W2p + ((size_t)(wave * 4) * 64 + lane) * 8;
#pragma unroll 4
    for (int kt = 0; kt < 12; ++kt) {
      bf16x8 a0 = *(const bf16x8*)&Hs[((kt * 2 + 0) * 64 + lane) * 8];
      bf16x8 a1 = *(const bf16x8*)&Hs[((kt * 2 + 1) * 64 + lane) * 8];
#pragma unroll
      for (int j = 0; j < 4; ++j) {
        bf16x8 bf = *(const bf16x8*)(wb + (size_t)kt * 8192 + j * 512);
        acc2[0][j] = __builtin_amdgcn_mfma_f32_16x16x32_bf16(a0, bf, acc2[0][j], 0, 0, 0);
        acc2[1][j] = __builtin_amdgcn_mfma_f32_16x16x32_bf16(a1, bf, acc2[1][j], 0, 0, 0);
      }
    }
  }

  // ---- epilogue 2: bias + store ----
  {
    float bload[4];
#pragma unroll
    for (int j = 0; j < 4; ++j)
      bload[j] = b2[wave * 64 + j * 16 + (lane & 15)];
#pragma unroll
    for (int mt = 0; mt < 2; ++mt) {
#pragma unroll
      for (int r = 0; r < 4; ++r) {
        int t = t0 + mt * 16 + (lane >> 4) * 4 + r;
        if (t < T) {
#pragma unroll
          for (int j = 0; j < 4; ++j) {
            int c = wave * 64 + j * 16 + (lane & 15);
            out[(size_t)t * 256 + c] = acc2[mt][j][r] + bload[j];
          }
        }
      }
    }
  }
}

// ---------------------------------------------------------------------------
extern "C" void kernel_launch(void* const* d_in, const int* in_sizes, int n_in,
                              void* d_out, int out_size, void* d_ws, size_t ws_size,
                              hipStream_t stream)
{
  const float* z      = (const float*)d_in[0];
  const float* keyW1  = (const float*)d_in[1];
  const float* keyb1  = (const float*)d_in[2];
  const float* keyg1  = (const float*)d_in[3];
  const float* keybe1 = (const float*)d_in[4];
  const float* keyW2  = (const float*)d_in[5];
  const float* keyb2  = (const float*)d_in[6];
  const float* decW1  = (const float*)d_in[7];
  const float* decb1  = (const float*)d_in[8];
  const float* decW2  = (const float*)d_in[9];
  const float* decb2  = (const float*)d_in[10];
  const float* spW1   = (const float*)d_in[11];
  const float* spb1   = (const float*)d_in[12];
  const float* spg1   = (const float*)d_in[13];
  const float* spbe1  = (const float*)d_in[14];
  const float* spW2   = (const float*)d_in[15];
  const float* spb2   = (const float*)d_in[16];

  const int T = out_size / (DIM + 1);   // out = x[T,256] ++ batch[T]

  char* ws = (char*)d_ws;
  int*   n_arr  = (int*)(ws);                 // 32768 ints
  int*   starts = (int*)(ws + 131072);        // 32769 ints
  float* ktab   = (float*)(ws + 262160);      // 17*512 f32
  short* W1p    = (short*)(ws + 296976);      // 512*384 bf16 = 393216 B
  short* W2p    = (short*)(ws + 690192);      // 384*256 bf16 = 196608 B
  int*   bi     = (int*)(ws + 886800);        // T ints
  size_t kioff  = 886800 + (((size_t)T * 4 + 15) / 16) * 16;
  int*   ki     = (int*)(ws + kioff);         // T ints

  float* outF = (float*)d_out;

  sizepred_kernel<<<B_N / 16, 320, 0, stream>>>(z, spW1, spb1, spg1, spbe1, spW2, spb2, n_arr);
  pack_kernel<<<576, 64, 0, stream>>>(decW1, decW2, W1p, W2p);
  scan_kernel<<<1, 1024, 0, stream>>>(n_arr, starts);
  keys_kernel<<<MAXN, 320, 0, stream>>>(keyW1, keyb1, keyg1, keybe1, keyW2, keyb2, ktab);
  scatter_kernel<<<B_N / 256, 256, 0, stream>>>(n_arr, starts, bi, ki, outF, T);
  if (T > 0)
    decoder_kernel<<<(T + 31) / 32, 256, 0, stream>>>(z, ktab, W1p, decb1, W2p, decb2, bi, ki, outF, T);
}